// Round 6
// baseline (26.201 us; speedup 1.0000x reference)
//
#include <hip/hip_runtime.h>

#define MAX_NODE 511
#define SLOTS (MAX_NODE + 1)   // 512
#define CDIM 1024              // channels (f32)
#define CPR  (CDIM / 4)        // 256 float4 per row
#define RPB  8                 // rows per block (SLOTS % RPB == 0 -> all rows same b)

typedef float f32x4 __attribute__((ext_vector_type(4)));

// Grid: (B*SLOTS/RPB)=2048 blocks x 256 threads. Each block: 8 consecutive rows
// of one graph b. One wave-parallel prefix per block; 8 independent 4 KiB
// load->store chains per thread with register-resident addressing.
__global__ __launch_bounds__(256)
void graph_embed_kernel(const float* __restrict__ patch,   // [total_nodes, CDIM]
                        const float* __restrict__ cent,    // [total_nodes, 2]
                        const float* __restrict__ img,     // [B, CDIM]
                        const int*   __restrict__ nn,      // [B]
                        float* __restrict__ out, int B) {
    const int rb    = blockIdx.x * RPB;   // first flattened row (b*SLOTS + slot)
    const int b     = rb >> 9;            // / SLOTS
    const int slot0 = rb & (SLOTS - 1);
    const int t     = threadIdx.x;
    const int lane  = t & 63;

    // Wave-parallel exclusive prefix: off = sum(nn[0..b-1]), n = nn[b].
    int v = (lane < B) ? nn[lane] : 0;
    const int n = __shfl(v, b, 64);
    int c = (lane < b) ? v : 0;
    #pragma unroll
    for (int d = 1; d < 64; d <<= 1) c += __shfl_xor(c, d, 64);
    const int off   = c;
    const int n_eff = (n < MAX_NODE) ? n : MAX_NODE;

    float* features = out;
    float* mask     = out + (size_t)B * SLOTS * CDIM;
    float* pos_x    = mask  + (size_t)B * SLOTS;
    float* pos_y    = pos_x + (size_t)B * SLOTS;

    const f32x4* patch4 = reinterpret_cast<const f32x4*>(patch);
    const f32x4* img4   = reinterpret_cast<const f32x4*>(img);
    f32x4*       feat4  = reinterpret_cast<f32x4*>(features);

    // Issue RPB independent loads, then RPB stores.
    f32x4 r[RPB];
    #pragma unroll
    for (int k = 0; k < RPB; ++k) {
        const int slot = slot0 + k;
        if (slot == 0) {
            r[k] = img4[(size_t)b * CPR + t];
        } else if (slot - 1 < n_eff) {
            r[k] = patch4[(size_t)(off + slot - 1) * CPR + t];
        } else {
            r[k] = (f32x4)(0.f);
        }
    }
    #pragma unroll
    for (int k = 0; k < RPB; ++k) {
        feat4[((size_t)b * SLOTS + slot0 + k) * CPR + t] = r[k];
    }

    // mask / pos: threads 0..RPB-1 each handle one row (consecutive dwords).
    if (t < RPB) {
        const int slot = slot0 + t;
        const float m = (slot >= n + 1 && n <= MAX_NODE) ? 1.0f : 0.0f;
        float px = 0.f, py = 0.f;
        if (slot >= 1 && slot - 1 < n_eff) {
            px = cent[(size_t)(off + slot - 1) * 2 + 0];
            py = cent[(size_t)(off + slot - 1) * 2 + 1];
        }
        const size_t mi = (size_t)b * SLOTS + slot;
        mask[mi]  = m;
        pos_x[mi] = px;
        pos_y[mi] = py;
    }
}

extern "C" void kernel_launch(void* const* d_in, const int* in_sizes, int n_in,
                              void* d_out, int out_size, void* d_ws, size_t ws_size,
                              hipStream_t stream) {
    const float* patch = (const float*)d_in[0];   // [total_nodes, 1024]
    const float* cent  = (const float*)d_in[1];   // [total_nodes, 2]
    const float* img   = (const float*)d_in[2];   // [B, 1024]
    const int*   nn    = (const int*)d_in[3];     // [B]
    float* out = (float*)d_out;

    const int B = in_sizes[3];
    const int nblocks = (B * SLOTS) / RPB;
    graph_embed_kernel<<<nblocks, 256, 0, stream>>>(patch, cent, img, nn, out, B);
}

// Round 7
// 20.560 us; speedup vs baseline: 1.2744x; 1.2744x over previous
//
#include <hip/hip_runtime.h>

#define MAX_NODE 511
#define SLOTS (MAX_NODE + 1)   // 512
#define CDIM 1024              // channels (f32)
#define CPR  (CDIM / 4)        // 256 float4 per row
#define RPB  4                 // rows per block (SLOTS % RPB == 0 -> all rows same b)

typedef float f32x4 __attribute__((ext_vector_type(4)));

// Main kernel: features copy only. Grid (B*SLOTS/RPB)=4096 x 256.
// Register-resident addressing (wave shfl prefix), nt-stores on the write-once
// features stream so it doesn't thrash L2 for the patch read side.
__global__ __launch_bounds__(256)
void graph_feat_kernel(const float* __restrict__ patch,   // [total_nodes, CDIM]
                       const float* __restrict__ img,     // [B, CDIM]
                       const int*   __restrict__ nn,      // [B]
                       float* __restrict__ features, int B) {
    const int rb    = blockIdx.x * RPB;   // first flattened row (b*SLOTS + slot)
    const int b     = rb >> 9;            // / SLOTS
    const int slot0 = rb & (SLOTS - 1);
    const int t     = threadIdx.x;
    const int lane  = t & 63;

    // Wave-parallel exclusive prefix: off = sum(nn[0..b-1]), n = nn[b].
    int v = (lane < B) ? nn[lane] : 0;
    const int n = __shfl(v, b, 64);
    int c = (lane < b) ? v : 0;
    #pragma unroll
    for (int d = 1; d < 64; d <<= 1) c += __shfl_xor(c, d, 64);
    const int off   = c;
    const int n_eff = (n < MAX_NODE) ? n : MAX_NODE;

    const f32x4* patch4 = reinterpret_cast<const f32x4*>(patch);
    const f32x4* img4   = reinterpret_cast<const f32x4*>(img);
    f32x4*       feat4  = reinterpret_cast<f32x4*>(features);

    f32x4 r[RPB];
    #pragma unroll
    for (int k = 0; k < RPB; ++k) {
        const int slot = slot0 + k;
        if (slot == 0) {
            r[k] = img4[(size_t)b * CPR + t];
        } else if (slot - 1 < n_eff) {
            r[k] = patch4[(size_t)(off + slot - 1) * CPR + t];
        } else {
            r[k] = (f32x4)(0.f);
        }
    }
    #pragma unroll
    for (int k = 0; k < RPB; ++k) {
        __builtin_nontemporal_store(
            r[k], feat4 + ((size_t)b * SLOTS + slot0 + k) * CPR + t);
    }
}

// Tail kernel: mask / pos_x / pos_y. Grid (B*SLOTS/256)=64 x 256, one row/thread.
__global__ __launch_bounds__(256)
void graph_mask_kernel(const float* __restrict__ cent,    // [total_nodes, 2]
                       const int*   __restrict__ nn,      // [B]
                       float* __restrict__ out, int B) {
    const int row  = blockIdx.x * 256 + threadIdx.x;     // b*SLOTS + slot
    const int b    = row >> 9;
    const int slot = row & (SLOTS - 1);
    const int lane = threadIdx.x & 63;

    int v = (lane < B) ? nn[lane] : 0;
    const int n = __shfl(v, b, 64);
    int c = (lane < b) ? v : 0;
    #pragma unroll
    for (int d = 1; d < 64; d <<= 1) c += __shfl_xor(c, d, 64);
    const int off   = c;
    const int n_eff = (n < MAX_NODE) ? n : MAX_NODE;

    float* mask  = out + (size_t)B * SLOTS * CDIM;
    float* pos_x = mask  + (size_t)B * SLOTS;
    float* pos_y = pos_x + (size_t)B * SLOTS;

    const float m = (slot >= n + 1 && n <= MAX_NODE) ? 1.0f : 0.0f;
    float px = 0.f, py = 0.f;
    if (slot >= 1 && slot - 1 < n_eff) {
        px = cent[(size_t)(off + slot - 1) * 2 + 0];
        py = cent[(size_t)(off + slot - 1) * 2 + 1];
    }
    mask[row]  = m;
    pos_x[row] = px;
    pos_y[row] = py;
}

extern "C" void kernel_launch(void* const* d_in, const int* in_sizes, int n_in,
                              void* d_out, int out_size, void* d_ws, size_t ws_size,
                              hipStream_t stream) {
    const float* patch = (const float*)d_in[0];   // [total_nodes, 1024]
    const float* cent  = (const float*)d_in[1];   // [total_nodes, 2]
    const float* img   = (const float*)d_in[2];   // [B, 1024]
    const int*   nn    = (const int*)d_in[3];     // [B]
    float* out = (float*)d_out;

    const int B = in_sizes[3];
    graph_feat_kernel<<<(B * SLOTS) / RPB, 256, 0, stream>>>(patch, img, nn, out, B);
    graph_mask_kernel<<<(B * SLOTS) / 256, 256, 0, stream>>>(cent, nn, out, B);
}

// Round 8
// 19.936 us; speedup vs baseline: 1.3143x; 1.0313x over previous
//
#include <hip/hip_runtime.h>

#define MAX_NODE 511
#define SLOTS (MAX_NODE + 1)   // 512
#define CDIM 1024              // channels (f32)
#define CPR  (CDIM / 4)        // 256 float4 per row
#define RPB  4                 // rows per block (SLOTS % RPB == 0 -> all rows same b)

typedef float f32x4 __attribute__((ext_vector_type(4)));

// Grid (B*SLOTS/RPB)=4096 x 256, single launch. 4 consecutive rows of one graph
// per block; wave-parallel shfl prefix for off/n; 4 independent load->store
// chains; mask/pos fused on threads 0..3. __launch_bounds__(256,8) caps VGPR
// at 64 to guarantee 8 waves/SIMD.
__global__ __launch_bounds__(256, 8)
void graph_embed_kernel(const float* __restrict__ patch,   // [total_nodes, CDIM]
                        const float* __restrict__ cent,    // [total_nodes, 2]
                        const float* __restrict__ img,     // [B, CDIM]
                        const int*   __restrict__ nn,      // [B]
                        float* __restrict__ out, int B) {
    const int rb    = blockIdx.x * RPB;   // first flattened row (b*SLOTS + slot)
    const int b     = rb >> 9;            // / SLOTS
    const int slot0 = rb & (SLOTS - 1);
    const int t     = threadIdx.x;
    const int lane  = t & 63;

    // Wave-parallel exclusive prefix: off = sum(nn[0..b-1]), n = nn[b].
    int v = (lane < B) ? nn[lane] : 0;
    const int n = __shfl(v, b, 64);
    int c = (lane < b) ? v : 0;
    #pragma unroll
    for (int d = 1; d < 64; d <<= 1) c += __shfl_xor(c, d, 64);
    const int off   = c;
    const int n_eff = (n < MAX_NODE) ? n : MAX_NODE;

    const f32x4* patch4 = reinterpret_cast<const f32x4*>(patch);
    const f32x4* img4   = reinterpret_cast<const f32x4*>(img);
    f32x4*       feat4  = reinterpret_cast<f32x4*>(out);

    f32x4 r[RPB];
    #pragma unroll
    for (int k = 0; k < RPB; ++k) {
        const int slot = slot0 + k;
        if (slot == 0) {
            r[k] = img4[(size_t)b * CPR + t];
        } else if (slot - 1 < n_eff) {
            r[k] = patch4[(size_t)(off + slot - 1) * CPR + t];
        } else {
            r[k] = (f32x4)(0.f);
        }
    }
    #pragma unroll
    for (int k = 0; k < RPB; ++k) {
        feat4[((size_t)b * SLOTS + slot0 + k) * CPR + t] = r[k];
    }

    // mask / pos: threads 0..RPB-1, one row each (consecutive dwords).
    if (t < RPB) {
        float* mask  = out + (size_t)B * SLOTS * CDIM;
        float* pos_x = mask  + (size_t)B * SLOTS;
        float* pos_y = pos_x + (size_t)B * SLOTS;
        const int slot = slot0 + t;
        const float m = (slot >= n + 1 && n <= MAX_NODE) ? 1.0f : 0.0f;
        float px = 0.f, py = 0.f;
        if (slot >= 1 && slot - 1 < n_eff) {
            px = cent[(size_t)(off + slot - 1) * 2 + 0];
            py = cent[(size_t)(off + slot - 1) * 2 + 1];
        }
        const size_t mi = (size_t)b * SLOTS + slot;
        mask[mi]  = m;
        pos_x[mi] = px;
        pos_y[mi] = py;
    }
}

extern "C" void kernel_launch(void* const* d_in, const int* in_sizes, int n_in,
                              void* d_out, int out_size, void* d_ws, size_t ws_size,
                              hipStream_t stream) {
    const float* patch = (const float*)d_in[0];   // [total_nodes, 1024]
    const float* cent  = (const float*)d_in[1];   // [total_nodes, 2]
    const float* img   = (const float*)d_in[2];   // [B, 1024]
    const int*   nn    = (const int*)d_in[3];     // [B]
    float* out = (float*)d_out;

    const int B = in_sizes[3];
    graph_embed_kernel<<<(B * SLOTS) / RPB, 256, 0, stream>>>(patch, cent, img, nn, out, B);
}